// Round 6
// baseline (450.842 us; speedup 1.0000x reference)
//
#include <hip/hip_runtime.h>
#include <hip/hip_bf16.h>

#define DEVI __device__ __forceinline__

typedef __attribute__((ext_vector_type(8))) short short8;
typedef __attribute__((ext_vector_type(4))) float floatx4;

#define Bn 16
#define Cn 512
#define Sn 32
#define Hn 8
#define Dn 64
#define SEQn 1024

DEVI float bf2f(ushort u) {
    union { unsigned int i; float f; } v; v.i = ((unsigned int)u) << 16; return v.f;
}
DEVI ushort f2bf(float f) {
    union { float f; unsigned int i; } v; v.f = f;
    unsigned int x = v.i;
    return (ushort)((x + 0x7fffu + ((x >> 16) & 1u)) >> 16);   // RNE
}
DEVI ushort f2bf_rhu(float f) {                 // round-half-up: 2 VALU ops
    union { float f; unsigned int i; } v; v.f = f;
    return (ushort)((v.i + 0x8000u) >> 16);
}

DEVI void gload_lds16(const ushort* g, ushort* l) {
    __builtin_amdgcn_global_load_lds(
        (const __attribute__((address_space(1))) void*)g,
        (__attribute__((address_space(3))) void*)l, 16, 0, 0);
}

// ---------------------------------------------------------------------------
__global__ __launch_bounds__(256) void cvt2_kernel(const float* __restrict__ b,
                                                   ushort* __restrict__ db)
{
    int i = blockIdx.x * 256 + threadIdx.x;
    db[i] = f2bf(b[i]);
}

// ---------------------------------------------------------------------------
// Per-head bias max (scaled by log2e) + zero-init Kmax accumulators.
__global__ __launch_bounds__(256) void maxpb_kernel(const float* __restrict__ pb,
                                                    float* __restrict__ Bmax,
                                                    int* __restrict__ Kmaxi)
{
    const int h = blockIdx.x, t = threadIdx.x;
    float m = -1e30f;
    for (int n = t; n < 3969; n += 256) m = fmaxf(m, pb[n * 8 + h]);
    __shared__ float sm[256];
    sm[t] = m; __syncthreads();
    for (int s = 128; s > 0; s >>= 1) {
        if (t < s) sm[t] = fmaxf(sm[t], sm[t + s]);
        __syncthreads();
    }
    if (t == 0) Bmax[h] = 1.44269504f * sm[0];
    if (h == 0 && t < 128) Kmaxi[t] = 0;
}

// ---------------------------------------------------------------------------
// LayerNorm over channels (C=512) per pixel; fp32 in, writes xn bf16 [B][SEQ][C]
__global__ __launch_bounds__(256) void ln_kernel(const float* __restrict__ x,
                                                 const float* __restrict__ scale,
                                                 ushort* __restrict__ xn)
{
    const int blk = blockIdx.x;
    const int b = blk >> 4;
    const int p0 = (blk & 15) * 64;
    const int t = threadIdx.x, p = t & 63, cg = t >> 6;
    const float* xb = x + (size_t)b * Cn * SEQn + p0 + p;

    float sum = 0.f, sq = 0.f;
    #pragma unroll 16
    for (int c = cg * 128; c < cg * 128 + 128; c++) {
        float v = xb[(size_t)c * SEQn];
        sum += v; sq += v * v;
    }
    __shared__ float rs[4][64], rq[4][64], mu_[64], rstd_[64];
    rs[cg][p] = sum; rq[cg][p] = sq;
    __syncthreads();
    if (t < 64) {
        float s  = rs[0][t] + rs[1][t] + rs[2][t] + rs[3][t];
        float q2 = rq[0][t] + rq[1][t] + rq[2][t] + rq[3][t];
        float mu = s * (1.f / 512.f);
        float var = q2 * (1.f / 512.f) - mu * mu;
        mu_[t] = mu;
        rstd_[t] = rsqrtf(var + 1e-5f);
    }
    __syncthreads();
    const float mu = mu_[p], rstd = rstd_[p];
    __shared__ ushort tile[64 * 132];
    ushort* xnb = xn + ((size_t)b * SEQn + p0) * Cn;
    for (int it = 0; it < 4; it++) {
        int cb = it * 128;
        #pragma unroll 8
        for (int j = 0; j < 32; j++) {
            int c = cb + cg * 32 + j;
            float v = (xb[(size_t)c * SEQn] - mu) * rstd * scale[c];
            tile[p * 132 + cg * 32 + j] = f2bf(v);
        }
        __syncthreads();
        #pragma unroll
        for (int qq = 0; qq < 4; qq++) {
            int lin = (t + qq * 256) * 8;
            int pp = lin >> 7, cc = lin & 127;
            const ushort* src = &tile[pp * 132 + cc];
            uint2 a  = *(const uint2*)src;
            uint2 b2 = *(const uint2*)(src + 4);
            uint4 o; o.x = a.x; o.y = a.y; o.z = b2.x; o.w = b2.y;
            *(uint4*)&xnb[(size_t)pp * Cn + cb + cc] = o;
        }
        __syncthreads();
    }
}

// ---------------------------------------------------------------------------
// Batched GEMM, B^T input: C[b][m][n] = sum_k A[m][k] * Bm[b][n][k].
__global__ __launch_bounds__(256) void gemm_bt(const ushort* __restrict__ A,
                                               const ushort* __restrict__ Bm,
                                               void* __restrict__ Cv,
                                               int M, int N, int K, int f32out)
{
    __shared__ __align__(16) ushort As[128 * 32];
    __shared__ __align__(16) ushort Bs[128 * 32];
    const int t = threadIdx.x;
    const int m0 = blockIdx.y * 128, n0 = blockIdx.x * 128;
    const ushort* Bb = Bm + (size_t)blockIdx.z * N * K;
    const int lane = t & 63, wave = t >> 6;
    const int wm = (wave & 1) * 64, wn = (wave >> 1) * 64;
    const int lm = lane & 15, qd = lane >> 4;

    floatx4 acc[4][4];
    #pragma unroll
    for (int i = 0; i < 4; i++)
        #pragma unroll
        for (int j = 0; j < 4; j++) acc[i][j] = (floatx4){0.f, 0.f, 0.f, 0.f};

    const int sm = t & 127;
    const int sc = t >> 7;

    for (int ks = 0; ks < K; ks += 32) {
        const ushort* ga = A  + (size_t)(m0 + sm) * K + ks;
        const ushort* gb = Bb + (size_t)(n0 + sm) * K + ks;
        gload_lds16(ga + sc * 8,       &As[(size_t)t * 8]);
        gload_lds16(ga + (sc + 2) * 8, &As[((size_t)t + 256) * 8]);
        gload_lds16(gb + sc * 8,       &Bs[(size_t)t * 8]);
        gload_lds16(gb + (sc + 2) * 8, &Bs[((size_t)t + 256) * 8]);
        __syncthreads();
        short8 af[4], bfv[4];
        #pragma unroll
        for (int i = 0; i < 4; i++)
            af[i] = *(const short8*)&As[(qd * 128 + wm + i * 16 + lm) * 8];
        #pragma unroll
        for (int j = 0; j < 4; j++)
            bfv[j] = *(const short8*)&Bs[(qd * 128 + wn + j * 16 + lm) * 8];
        #pragma unroll
        for (int i = 0; i < 4; i++)
            #pragma unroll
            for (int j = 0; j < 4; j++)
                acc[i][j] = __builtin_amdgcn_mfma_f32_16x16x32_bf16(af[i], bfv[j], acc[i][j], 0, 0, 0);
        __syncthreads();
    }
    if (f32out) {
        float* Cb = (float*)Cv + (size_t)blockIdx.z * M * N;
        #pragma unroll
        for (int i = 0; i < 4; i++) {
            int row0 = m0 + wm + i * 16 + qd * 4;
            #pragma unroll
            for (int j = 0; j < 4; j++) {
                int col = n0 + wn + j * 16 + lm;
                #pragma unroll
                for (int r = 0; r < 4; r++)
                    Cb[(size_t)(row0 + r) * N + col] = acc[i][j][r];
            }
        }
    } else {
        ushort* Cb = (ushort*)Cv + (size_t)blockIdx.z * M * N;
        #pragma unroll
        for (int i = 0; i < 4; i++) {
            int row0 = m0 + wm + i * 16 + qd * 4;
            #pragma unroll
            for (int j = 0; j < 4; j++) {
                int col = n0 + wn + j * 16 + lm;
                #pragma unroll
                for (int r = 0; r < 4; r++)
                    Cb[(size_t)(row0 + r) * N + col] = f2bf(acc[i][j][r]);
            }
        }
    }
}

// ---------------------------------------------------------------------------
// Depthwise 3x3 + bias v2: LDS-staged input (f32, zero-padded halo).
__global__ __launch_bounds__(256) void dwconv_kernel(const ushort* __restrict__ qkv,
    const float* __restrict__ wq, const float* __restrict__ bq,
    const float* __restrict__ wk, const float* __restrict__ bk,
    const float* __restrict__ wv, const float* __restrict__ bv,
    ushort* __restrict__ out, float* __restrict__ qn, int* __restrict__ Kmaxi)
{
    const int rp = blockIdx.x;             // 0..15 : 2 output rows
    const int cg = blockIdx.y;             // 0..23 : type*8 + head
    const int b  = blockIdx.z;
    const int type = cg >> 3, head = cg & 7;
    const float* w  = (type == 0) ? wq : (type == 1) ? wk : wv;
    const float* bs = (type == 0) ? bq : (type == 1) ? bk : bv;
    const int t = threadIdx.x;
    const int y0 = rp * 2;

    __shared__ __align__(16) float Ls[64 * 4 * 36];    // 36864 B

    {
        float4 z = (float4){0.f, 0.f, 0.f, 0.f};
        *(float4*)&Ls[(t >> 2) * 144 + (t & 3) * 36 + 32] = z;
    }
    const ushort* srcb = qkv + ((size_t)b * 1536 + type * 512 + head * 64) * SEQn;
    #pragma unroll
    for (int k = 0; k < 4; k++) {
        int tt = t + k * 256;
        int ch = tt >> 4, row = (tt >> 2) & 3, sg = tt & 3;
        int yy = y0 - 1 + row;
        float4 lo = (float4){0.f, 0.f, 0.f, 0.f}, hi = lo;
        if (yy >= 0 && yy <= 31) {
            uint4 g = *(const uint4*)&srcb[(size_t)ch * SEQn + yy * 32 + sg * 8];
            lo.x = bf2f((ushort)(g.x & 0xffffu)); lo.y = bf2f((ushort)(g.x >> 16));
            lo.z = bf2f((ushort)(g.y & 0xffffu)); lo.w = bf2f((ushort)(g.y >> 16));
            hi.x = bf2f((ushort)(g.z & 0xffffu)); hi.y = bf2f((ushort)(g.z >> 16));
            hi.z = bf2f((ushort)(g.w & 0xffffu)); hi.w = bf2f((ushort)(g.w >> 16));
        }
        float* dst = &Ls[ch * 144 + row * 36 + sg * 8];
        *(float4*)&dst[0] = lo;
        *(float4*)&dst[4] = hi;
    }
    __syncthreads();

    const int oct = t >> 5, x = t & 31;
    const int cm = (x == 0)  ? 33 : x - 1;
    const int cp = (x == 31) ? 33 : x + 1;
    float a0[8], a1[8];
    #pragma unroll
    for (int i = 0; i < 8; i++) {
        int ch = oct * 8 + i;
        int chl = head * 64 + ch;
        const float* wc = &w[chl * 9];
        float w0 = wc[0], w1 = wc[1], w2 = wc[2];
        float w3 = wc[3], w4 = wc[4], w5 = wc[5];
        float w6 = wc[6], w7 = wc[7], w8 = wc[8];
        float bias = bs[chl];
        const float* L = &Ls[ch * 144];
        #pragma unroll
        for (int y = 0; y < 2; y++) {
            const float* r0 = L + (y + 0) * 36;
            const float* r1 = L + (y + 1) * 36;
            const float* r2 = L + (y + 2) * 36;
            float acc = bias;
            acc += r0[cm] * w0 + r0[x] * w1 + r0[cp] * w2;
            acc += r1[cm] * w3 + r1[x] * w4 + r1[cp] * w5;
            acc += r2[cm] * w6 + r2[x] * w7 + r2[cp] * w8;
            if (type == 0) acc *= 0.18033688f;   // 0.125 * log2(e)
            if (y == 0) a0[i] = acc; else a1[i] = acc;
        }
    }
    __syncthreads();
    float* tile = Ls;
    #pragma unroll
    for (int i = 0; i < 8; i++) {
        tile[(0 * 32 + x) * 65 + oct * 8 + i] = a0[i];
        tile[(1 * 32 + x) * 65 + oct * 8 + i] = a1[i];
    }
    __syncthreads();

    if (t < 64) {
        float s2 = 0.f;
        #pragma unroll 16
        for (int d = 0; d < 64; d++) { float v = tile[t * 65 + d]; s2 += v * v; }
        if (type == 0) {
            qn[(((size_t)b * 8 + head) << 10) + rp * 64 + t] = sqrtf(s2);
        } else if (type == 1) {
            float m = s2;
            m = fmaxf(m, __shfl_xor(m, 1));
            m = fmaxf(m, __shfl_xor(m, 2));
            m = fmaxf(m, __shfl_xor(m, 4));
            m = fmaxf(m, __shfl_xor(m, 8));
            m = fmaxf(m, __shfl_xor(m, 16));
            m = fmaxf(m, __shfl_xor(m, 32));
            if (t == 0) atomicMax(&Kmaxi[b * 8 + head], __float_as_int(sqrtf(m)));
        }
    }
    if (type < 2) {
        size_t base = ((((size_t)type * Bn + b) * Hn + head) * SEQn + rp * 64) * Dn;
        #pragma unroll
        for (int it2 = 0; it2 < 2; it2++) {
            int chunk = t + it2 * 256;
            int p = chunk >> 3, d0 = (chunk & 7) * 8;
            ushort tmp[8];
            #pragma unroll
            for (int e = 0; e < 8; e++) tmp[e] = f2bf(tile[p * 65 + d0 + e]);
            *(uint4*)&out[base + (size_t)p * 64 + d0] = *(const uint4*)tmp;
        }
    } else {
        size_t base = (((size_t)2 * Bn + b) * Hn + head) * (size_t)SEQn * Dn;
        #pragma unroll
        for (int it2 = 0; it2 < 2; it2++) {
            int chunk = t + it2 * 256;
            int d = chunk >> 3, pp = (chunk & 7) * 8;
            ushort tmp[8];
            #pragma unroll
            for (int e = 0; e < 8; e++) tmp[e] = f2bf(tile[(pp + e) * 65 + d]);
            *(uint4*)&out[base + (size_t)d * SEQn + rp * 64 + pp] = *(const uint4*)tmp;
        }
    }
}

// ---------------------------------------------------------------------------
// Bias in MFMA-fragment order, fp32, scaled by log2e.
__global__ __launch_bounds__(256) void bias_gather(const int* __restrict__ idx,
                                                   const float* __restrict__ pb,
                                                   float* __restrict__ rbF)
{
    const int g = blockIdx.x * 256 + threadIdx.x;   // 524288 total
    const int lane = g & 63;
    const int jt = (g >> 6) & 15;
    const int ib = (g >> 10) & 63;
    const int h  = (g >> 16) & 7;
    const int lm = lane & 15, qd = lane >> 4;
    float tmp[16];
    #pragma unroll
    for (int v = 0; v < 16; v++) {
        int r = v & 3, jb = v >> 2;
        int i = ib * 16 + qd * 4 + r;
        int j = jt * 64 + jb * 16 + lm;
        tmp[v] = 1.44269504f * pb[idx[i * 1024 + j] * 8 + h];
    }
    float* dst = rbF + ((size_t)g << 4);
    *(float4*)&dst[0]  = *(const float4*)&tmp[0];
    *(float4*)&dst[4]  = *(const float4*)&tmp[4];
    *(float4*)&dst[8]  = *(const float4*)&tmp[8];
    *(float4*)&dst[12] = *(const float4*)&tmp[12];
}

// ---------------------------------------------------------------------------
// Flash attention v4: j-tile=128 (two interleaved 64-j chains), bias via MFMA
// C-init, fixed exp bound, l via ones-MFMA, 2-op bf16 cvt, early bias prefetch.
__global__ __launch_bounds__(256, 3) void attn_kernel(const ushort* __restrict__ qkvs,
                                                      const float* __restrict__ rbF,
                                                      const float* __restrict__ qn,
                                                      const float* __restrict__ Bmax,
                                                      const int* __restrict__ Kmaxi,
                                                      ushort* __restrict__ ao)
{
    const int n = blockIdx.x;
    const int h = n & 7, b = (n >> 3) & 15, qb = n >> 7;
    const int t = threadIdx.x, lane = t & 63, wave = t >> 6;
    const int lm = lane & 15, qd = lane >> 4;
    const int q0 = qb * 64;
    const int ib = qb * 4 + wave;
    const int i0 = q0 + wave * 16;
    const int bh = b * 8 + h;
    const size_t bhs = (size_t)bh * SEQn * Dn;
    const size_t tsz = (size_t)Bn * Hn * SEQn * Dn;
    const ushort* Q  = qkvs + bhs;
    const ushort* Kp = qkvs + tsz + bhs;          // [SEQ][D]
    const ushort* Vg = qkvs + 2 * tsz + bhs;      // [D][SEQ]

    __shared__ __align__(16) ushort Ks[128 * 72];      // 18432 B, [j][d]
    __shared__ __align__(16) ushort Vt[64 * 136];      // 17408 B, [d][j]
    __shared__ __align__(16) ushort Ps[4 * 16 * 136];  // 17408 B, per-wave [i][j]
    ushort* Psw = &Ps[wave * 16 * 136];

    short8 qf0 = *(const short8*)&Q[(size_t)(i0 + lm) * 64 + qd * 8];
    short8 qf1 = *(const short8*)&Q[(size_t)(i0 + lm) * 64 + 32 + qd * 8];

    floatx4 Mneg4;
    {
        float kmx = __int_as_float(Kmaxi[bh]);
        float bmx = Bmax[h];
        #pragma unroll
        for (int r = 0; r < 4; r++)
            Mneg4[r] = -(bmx + qn[((size_t)bh << 10) + i0 + qd * 4 + r] * kmx);
    }

    short8 ones;
    #pragma unroll
    for (int e = 0; e < 8; e++) ones[e] = (short)0x3F80;   // bf16 1.0

    floatx4 oa[4], lacc;
    #pragma unroll
    for (int d = 0; d < 4; d++) oa[d] = (floatx4){0.f, 0.f, 0.f, 0.f};
    lacc = (floatx4){0.f, 0.f, 0.f, 0.f};

    // staging indices: K 128 rows x 64 cols; V 64 d-rows x 128 j-cols
    const int kr = t >> 3, kc = (t & 7) * 8;
    const int vr = t >> 4, vc = (t & 15) * 8;

    uint4 kpre[4], vpre[4];
    #pragma unroll
    for (int s = 0; s < 4; s++) {
        kpre[s] = *(const uint4*)&Kp[(size_t)(kr + s * 32) * 64 + kc];
        vpre[s] = *(const uint4*)&Vg[(size_t)(vr + s * 16) * SEQn + vc];
    }

    const float* bpb = rbF + ((((size_t)h * 64 + ib) * 16) * 64 + lane) * 16;

    for (int jt = 0; jt < 8; jt++) {
        // bias prefetch for this 128-j tile (two 64-j fragments, 32 floats)
        const float* bp = bpb + (size_t)jt * 2048;
        float4 bl[8];
        #pragma unroll
        for (int v = 0; v < 4; v++) bl[v] = *(const float4*)(bp + v * 4);
        #pragma unroll
        for (int v = 0; v < 4; v++) bl[4 + v] = *(const float4*)(bp + 1024 + v * 4);

        __syncthreads();
        #pragma unroll
        for (int s = 0; s < 4; s++) {
            *(uint4*)&Ks[(kr + s * 32) * 72 + kc] = kpre[s];
            *(uint4*)&Vt[(vr + s * 16) * 136 + vc] = vpre[s];
        }
        if (jt < 7) {
            int j1 = (jt + 1) * 128;
            #pragma unroll
            for (int s = 0; s < 4; s++) {
                kpre[s] = *(const uint4*)&Kp[(size_t)(j1 + kr + s * 32) * 64 + kc];
                vpre[s] = *(const uint4*)&Vg[(size_t)(vr + s * 16) * SEQn + j1 + vc];
            }
        }
        __syncthreads();

        // QK^T, bias+Mneg folded into the accumulator init
        floatx4 s[8];
        #pragma unroll
        for (int jj = 0; jj < 8; jj++) {
            floatx4 z;
            z[0] = bl[jj].x + Mneg4[0];
            z[1] = bl[jj].y + Mneg4[1];
            z[2] = bl[jj].z + Mneg4[2];
            z[3] = bl[jj].w + Mneg4[3];
            short8 k0 = *(const short8*)&Ks[(jj * 16 + lm) * 72 + qd * 8];
            short8 k1 = *(const short8*)&Ks[(jj * 16 + lm) * 72 + 32 + qd * 8];
            z = __builtin_amdgcn_mfma_f32_16x16x32_bf16(qf0, k0, z, 0, 0, 0);
            z = __builtin_amdgcn_mfma_f32_16x16x32_bf16(qf1, k1, z, 0, 0, 0);
            s[jj] = z;
        }
        // exp2 + 2-op cvt + Ps write (arg <= 0 by construction)
        #pragma unroll
        for (int jj = 0; jj < 8; jj++) {
            #pragma unroll
            for (int r = 0; r < 4; r++) {
                float e = __builtin_amdgcn_exp2f(s[jj][r]);
                Psw[(qd * 4 + r) * 136 + jj * 16 + lm] = f2bf_rhu(e);
            }
        }
        // P fragments (A-layout over K=128) + l-sum + PV
        short8 pf[4];
        #pragma unroll
        for (int c = 0; c < 4; c++)
            pf[c] = *(const short8*)&Psw[lm * 136 + c * 32 + qd * 8];
        #pragma unroll
        for (int c = 0; c < 4; c++)
            lacc = __builtin_amdgcn_mfma_f32_16x16x32_bf16(pf[c], ones, lacc, 0, 0, 0);
        #pragma unroll
        for (int d = 0; d < 4; d++) {
            #pragma unroll
            for (int c = 0; c < 4; c++) {
                short8 vb = *(const short8*)&Vt[(d * 16 + lm) * 136 + c * 32 + qd * 8];
                oa[d] = __builtin_amdgcn_mfma_f32_16x16x32_bf16(pf[c], vb, oa[d], 0, 0, 0);
            }
        }
    }
    // epilogue: Ot overlays each wave's own Ps rows (stride 136) — in-order LDS,
    // no barrier needed before the overwrite.
    #pragma unroll
    for (int r = 0; r < 4; r++) {
        float inv = 1.f / fmaxf(lacc[r], 1e-30f);
        #pragma unroll
        for (int d = 0; d < 4; d++)
            Ps[(wave * 16 + qd * 4 + r) * 136 + d * 16 + lm] = f2bf(oa[d][r] * inv);
    }
    __syncthreads();
    ushort* aob = ao + ((size_t)b * SEQn + q0) * Cn + h * Dn;
    #pragma unroll
    for (int it = 0; it < 2; it++) {
        int chunk = t + it * 256;
        int i = chunk >> 3, d0 = (chunk & 7) * 8;
        *(uint4*)&aob[(size_t)i * Cn + d0] = *(const uint4*)&Ps[i * 136 + d0];
    }
}

// ---------------------------------------------------------------------------
extern "C" void kernel_launch(void* const* d_in, const int* in_sizes, int n_in,
                              void* d_out, int out_size, void* d_ws, size_t ws_size,
                              hipStream_t stream) {
    (void)in_sizes; (void)n_in; (void)out_size; (void)ws_size;
    const float* x      = (const float*)d_in[0];
    const float* scale  = (const float*)d_in[1];
    const float* w_qkv  = (const float*)d_in[2];
    const float* dw_w_q = (const float*)d_in[3];
    const float* dw_b_q = (const float*)d_in[4];
    const float* dw_w_k = (const float*)d_in[5];
    const float* dw_b_k = (const float*)d_in[6];
    const float* dw_w_v = (const float*)d_in[7];
    const float* dw_b_v = (const float*)d_in[8];
    const float* w_out  = (const float*)d_in[9];
    const float* pos_b  = (const float*)d_in[10];
    const int*   pos_i  = (const int*)d_in[11];
    float* out = (float*)d_out;

    char* ws = (char*)d_ws;
    const size_t MB = (size_t)1 << 20;
    ushort* qkv_raw = (ushort*)(ws);              // [0,48MB)
    ushort* qkvs    = (ushort*)(ws + 48 * MB);    // [48,96MB)
    ushort* xn      = (ushort*)(ws + 48 * MB);    // [48,64MB) dead before dwconv
    ushort* wqkv_bf = (ushort*)(ws + 64 * MB);    // [64,65.5MB)
    float*  rbF     = (float*)(ws);               // [0,32MB) after dwconv
    ushort* ao      = (ushort*)(ws + 32 * MB);    // [32,48MB)
    ushort* wout_bf = (ushort*)(ws + 96 * MB);    // [96,96.5MB)
    float*  qn      = (float*)(ws + 98 * MB);     // [98,98.5MB)
    float*  Bmax    = (float*)(ws + 99 * MB);
    int*    Kmaxi   = (int*)(ws + 99 * MB + 4096);

    hipLaunchKernelGGL(cvt2_kernel, dim3(3072), dim3(256), 0, stream, w_qkv, wqkv_bf);
    hipLaunchKernelGGL(cvt2_kernel, dim3(1024), dim3(256), 0, stream, w_out, wout_bf);
    hipLaunchKernelGGL(maxpb_kernel, dim3(8), dim3(256), 0, stream, pos_b, Bmax, Kmaxi);
    hipLaunchKernelGGL(ln_kernel, dim3(256), dim3(256), 0, stream, x, scale, xn);
    hipLaunchKernelGGL(gemm_bt, dim3(8, 12, 16), dim3(256), 0, stream,
                       wqkv_bf, xn, (void*)qkv_raw, 1536, 1024, 512, 0);
    hipLaunchKernelGGL(dwconv_kernel, dim3(16, 24, 16), dim3(256), 0, stream,
                       qkv_raw, dw_w_q, dw_b_q, dw_w_k, dw_b_k, dw_w_v, dw_b_v,
                       qkvs, qn, Kmaxi);
    hipLaunchKernelGGL(bias_gather, dim3(2048), dim3(256), 0, stream, pos_i, pos_b, rbF);
    hipLaunchKernelGGL(attn_kernel, dim3(2048), dim3(256), 0, stream,
                       qkvs, rbF, qn, Bmax, Kmaxi, ao);
    hipLaunchKernelGGL(gemm_bt, dim3(8, 4, 16), dim3(256), 0, stream,
                       wout_bf, ao, (void*)out, 512, 1024, 512, 1);
}

// Round 7
// 344.794 us; speedup vs baseline: 1.3076x; 1.3076x over previous
//
#include <hip/hip_runtime.h>
#include <hip/hip_bf16.h>

#define DEVI __device__ __forceinline__

typedef __attribute__((ext_vector_type(8))) short short8;
typedef __attribute__((ext_vector_type(4))) float floatx4;

#define Bn 16
#define Cn 512
#define Sn 32
#define Hn 8
#define Dn 64
#define SEQn 1024

DEVI float bf2f(ushort u) {
    union { unsigned int i; float f; } v; v.i = ((unsigned int)u) << 16; return v.f;
}
DEVI ushort f2bf(float f) {
    union { float f; unsigned int i; } v; v.f = f;
    unsigned int x = v.i;
    return (ushort)((x + 0x7fffu + ((x >> 16) & 1u)) >> 16);   // RNE
}
DEVI ushort f2bf_rhu(float f) {                 // round-half-up: 2 VALU ops
    union { float f; unsigned int i; } v; v.f = f;
    return (ushort)((v.i + 0x8000u) >> 16);
}

DEVI void gload_lds16(const ushort* g, ushort* l) {
    __builtin_amdgcn_global_load_lds(
        (const __attribute__((address_space(1))) void*)g,
        (__attribute__((address_space(3))) void*)l, 16, 0, 0);
}

// ---------------------------------------------------------------------------
__global__ __launch_bounds__(256) void cvt2_kernel(const float* __restrict__ b,
                                                   ushort* __restrict__ db)
{
    int i = blockIdx.x * 256 + threadIdx.x;
    db[i] = f2bf(b[i]);
}

// ---------------------------------------------------------------------------
// Per-head bias max (scaled by log2e) + zero-init Kmax accumulators.
__global__ __launch_bounds__(256) void maxpb_kernel(const float* __restrict__ pb,
                                                    float* __restrict__ Bmax,
                                                    int* __restrict__ Kmaxi)
{
    const int h = blockIdx.x, t = threadIdx.x;
    float m = -1e30f;
    for (int n = t; n < 3969; n += 256) m = fmaxf(m, pb[n * 8 + h]);
    __shared__ float sm[256];
    sm[t] = m; __syncthreads();
    for (int s = 128; s > 0; s >>= 1) {
        if (t < s) sm[t] = fmaxf(sm[t], sm[t + s]);
        __syncthreads();
    }
    if (t == 0) Bmax[h] = 1.44269504f * sm[0];
    if (h == 0 && t < 128) Kmaxi[t] = 0;
}

// ---------------------------------------------------------------------------
// LayerNorm over channels (C=512) per pixel; fp32 in, writes xn bf16 [B][SEQ][C]
__global__ __launch_bounds__(256) void ln_kernel(const float* __restrict__ x,
                                                 const float* __restrict__ scale,
                                                 ushort* __restrict__ xn)
{
    const int blk = blockIdx.x;
    const int b = blk >> 4;
    const int p0 = (blk & 15) * 64;
    const int t = threadIdx.x, p = t & 63, cg = t >> 6;
    const float* xb = x + (size_t)b * Cn * SEQn + p0 + p;

    float sum = 0.f, sq = 0.f;
    #pragma unroll 16
    for (int c = cg * 128; c < cg * 128 + 128; c++) {
        float v = xb[(size_t)c * SEQn];
        sum += v; sq += v * v;
    }
    __shared__ float rs[4][64], rq[4][64], mu_[64], rstd_[64];
    rs[cg][p] = sum; rq[cg][p] = sq;
    __syncthreads();
    if (t < 64) {
        float s  = rs[0][t] + rs[1][t] + rs[2][t] + rs[3][t];
        float q2 = rq[0][t] + rq[1][t] + rq[2][t] + rq[3][t];
        float mu = s * (1.f / 512.f);
        float var = q2 * (1.f / 512.f) - mu * mu;
        mu_[t] = mu;
        rstd_[t] = rsqrtf(var + 1e-5f);
    }
    __syncthreads();
    const float mu = mu_[p], rstd = rstd_[p];
    __shared__ ushort tile[64 * 132];
    ushort* xnb = xn + ((size_t)b * SEQn + p0) * Cn;
    for (int it = 0; it < 4; it++) {
        int cb = it * 128;
        #pragma unroll 8
        for (int j = 0; j < 32; j++) {
            int c = cb + cg * 32 + j;
            float v = (xb[(size_t)c * SEQn] - mu) * rstd * scale[c];
            tile[p * 132 + cg * 32 + j] = f2bf(v);
        }
        __syncthreads();
        #pragma unroll
        for (int qq = 0; qq < 4; qq++) {
            int lin = (t + qq * 256) * 8;
            int pp = lin >> 7, cc = lin & 127;
            const ushort* src = &tile[pp * 132 + cc];
            uint2 a  = *(const uint2*)src;
            uint2 b2 = *(const uint2*)(src + 4);
            uint4 o; o.x = a.x; o.y = a.y; o.z = b2.x; o.w = b2.y;
            *(uint4*)&xnb[(size_t)pp * Cn + cb + cc] = o;
        }
        __syncthreads();
    }
}

// ---------------------------------------------------------------------------
// Batched GEMM, B^T input: C[b][m][n] = sum_k A[m][k] * Bm[b][n][k].
__global__ __launch_bounds__(256) void gemm_bt(const ushort* __restrict__ A,
                                               const ushort* __restrict__ Bm,
                                               void* __restrict__ Cv,
                                               int M, int N, int K, int f32out)
{
    __shared__ __align__(16) ushort As[128 * 32];
    __shared__ __align__(16) ushort Bs[128 * 32];
    const int t = threadIdx.x;
    const int m0 = blockIdx.y * 128, n0 = blockIdx.x * 128;
    const ushort* Bb = Bm + (size_t)blockIdx.z * N * K;
    const int lane = t & 63, wave = t >> 6;
    const int wm = (wave & 1) * 64, wn = (wave >> 1) * 64;
    const int lm = lane & 15, qd = lane >> 4;

    floatx4 acc[4][4];
    #pragma unroll
    for (int i = 0; i < 4; i++)
        #pragma unroll
        for (int j = 0; j < 4; j++) acc[i][j] = (floatx4){0.f, 0.f, 0.f, 0.f};

    const int sm = t & 127;
    const int sc = t >> 7;

    for (int ks = 0; ks < K; ks += 32) {
        const ushort* ga = A  + (size_t)(m0 + sm) * K + ks;
        const ushort* gb = Bb + (size_t)(n0 + sm) * K + ks;
        gload_lds16(ga + sc * 8,       &As[(size_t)t * 8]);
        gload_lds16(ga + (sc + 2) * 8, &As[((size_t)t + 256) * 8]);
        gload_lds16(gb + sc * 8,       &Bs[(size_t)t * 8]);
        gload_lds16(gb + (sc + 2) * 8, &Bs[((size_t)t + 256) * 8]);
        __syncthreads();
        short8 af[4], bfv[4];
        #pragma unroll
        for (int i = 0; i < 4; i++)
            af[i] = *(const short8*)&As[(qd * 128 + wm + i * 16 + lm) * 8];
        #pragma unroll
        for (int j = 0; j < 4; j++)
            bfv[j] = *(const short8*)&Bs[(qd * 128 + wn + j * 16 + lm) * 8];
        #pragma unroll
        for (int i = 0; i < 4; i++)
            #pragma unroll
            for (int j = 0; j < 4; j++)
                acc[i][j] = __builtin_amdgcn_mfma_f32_16x16x32_bf16(af[i], bfv[j], acc[i][j], 0, 0, 0);
        __syncthreads();
    }
    if (f32out) {
        float* Cb = (float*)Cv + (size_t)blockIdx.z * M * N;
        #pragma unroll
        for (int i = 0; i < 4; i++) {
            int row0 = m0 + wm + i * 16 + qd * 4;
            #pragma unroll
            for (int j = 0; j < 4; j++) {
                int col = n0 + wn + j * 16 + lm;
                #pragma unroll
                for (int r = 0; r < 4; r++)
                    Cb[(size_t)(row0 + r) * N + col] = acc[i][j][r];
            }
        }
    } else {
        ushort* Cb = (ushort*)Cv + (size_t)blockIdx.z * M * N;
        #pragma unroll
        for (int i = 0; i < 4; i++) {
            int row0 = m0 + wm + i * 16 + qd * 4;
            #pragma unroll
            for (int j = 0; j < 4; j++) {
                int col = n0 + wn + j * 16 + lm;
                #pragma unroll
                for (int r = 0; r < 4; r++)
                    Cb[(size_t)(row0 + r) * N + col] = f2bf(acc[i][j][r]);
            }
        }
    }
}

// ---------------------------------------------------------------------------
// Depthwise 3x3 + bias v2: LDS-staged input (f32, zero-padded halo).
__global__ __launch_bounds__(256) void dwconv_kernel(const ushort* __restrict__ qkv,
    const float* __restrict__ wq, const float* __restrict__ bq,
    const float* __restrict__ wk, const float* __restrict__ bk,
    const float* __restrict__ wv, const float* __restrict__ bv,
    ushort* __restrict__ out, float* __restrict__ qn, int* __restrict__ Kmaxi)
{
    const int rp = blockIdx.x;             // 0..15 : 2 output rows
    const int cg = blockIdx.y;             // 0..23 : type*8 + head
    const int b  = blockIdx.z;
    const int type = cg >> 3, head = cg & 7;
    const float* w  = (type == 0) ? wq : (type == 1) ? wk : wv;
    const float* bs = (type == 0) ? bq : (type == 1) ? bk : bv;
    const int t = threadIdx.x;
    const int y0 = rp * 2;

    __shared__ __align__(16) float Ls[64 * 4 * 36];    // 36864 B

    {
        float4 z = (float4){0.f, 0.f, 0.f, 0.f};
        *(float4*)&Ls[(t >> 2) * 144 + (t & 3) * 36 + 32] = z;
    }
    const ushort* srcb = qkv + ((size_t)b * 1536 + type * 512 + head * 64) * SEQn;
    #pragma unroll
    for (int k = 0; k < 4; k++) {
        int tt = t + k * 256;
        int ch = tt >> 4, row = (tt >> 2) & 3, sg = tt & 3;
        int yy = y0 - 1 + row;
        float4 lo = (float4){0.f, 0.f, 0.f, 0.f}, hi = lo;
        if (yy >= 0 && yy <= 31) {
            uint4 g = *(const uint4*)&srcb[(size_t)ch * SEQn + yy * 32 + sg * 8];
            lo.x = bf2f((ushort)(g.x & 0xffffu)); lo.y = bf2f((ushort)(g.x >> 16));
            lo.z = bf2f((ushort)(g.y & 0xffffu)); lo.w = bf2f((ushort)(g.y >> 16));
            hi.x = bf2f((ushort)(g.z & 0xffffu)); hi.y = bf2f((ushort)(g.z >> 16));
            hi.z = bf2f((ushort)(g.w & 0xffffu)); hi.w = bf2f((ushort)(g.w >> 16));
        }
        float* dst = &Ls[ch * 144 + row * 36 + sg * 8];
        *(float4*)&dst[0] = lo;
        *(float4*)&dst[4] = hi;
    }
    __syncthreads();

    const int oct = t >> 5, x = t & 31;
    const int cm = (x == 0)  ? 33 : x - 1;
    const int cp = (x == 31) ? 33 : x + 1;
    float a0[8], a1[8];
    #pragma unroll
    for (int i = 0; i < 8; i++) {
        int ch = oct * 8 + i;
        int chl = head * 64 + ch;
        const float* wc = &w[chl * 9];
        float w0 = wc[0], w1 = wc[1], w2 = wc[2];
        float w3 = wc[3], w4 = wc[4], w5 = wc[5];
        float w6 = wc[6], w7 = wc[7], w8 = wc[8];
        float bias = bs[chl];
        const float* L = &Ls[ch * 144];
        #pragma unroll
        for (int y = 0; y < 2; y++) {
            const float* r0 = L + (y + 0) * 36;
            const float* r1 = L + (y + 1) * 36;
            const float* r2 = L + (y + 2) * 36;
            float acc = bias;
            acc += r0[cm] * w0 + r0[x] * w1 + r0[cp] * w2;
            acc += r1[cm] * w3 + r1[x] * w4 + r1[cp] * w5;
            acc += r2[cm] * w6 + r2[x] * w7 + r2[cp] * w8;
            if (type == 0) acc *= 0.18033688f;   // 0.125 * log2(e)
            if (y == 0) a0[i] = acc; else a1[i] = acc;
        }
    }
    __syncthreads();
    float* tile = Ls;
    #pragma unroll
    for (int i = 0; i < 8; i++) {
        tile[(0 * 32 + x) * 65 + oct * 8 + i] = a0[i];
        tile[(1 * 32 + x) * 65 + oct * 8 + i] = a1[i];
    }
    __syncthreads();

    if (t < 64) {
        float s2 = 0.f;
        #pragma unroll 16
        for (int d = 0; d < 64; d++) { float v = tile[t * 65 + d]; s2 += v * v; }
        if (type == 0) {
            qn[(((size_t)b * 8 + head) << 10) + rp * 64 + t] = sqrtf(s2);
        } else if (type == 1) {
            float m = s2;
            m = fmaxf(m, __shfl_xor(m, 1));
            m = fmaxf(m, __shfl_xor(m, 2));
            m = fmaxf(m, __shfl_xor(m, 4));
            m = fmaxf(m, __shfl_xor(m, 8));
            m = fmaxf(m, __shfl_xor(m, 16));
            m = fmaxf(m, __shfl_xor(m, 32));
            if (t == 0) atomicMax(&Kmaxi[b * 8 + head], __float_as_int(sqrtf(m)));
        }
    }
    if (type < 2) {
        size_t base = ((((size_t)type * Bn + b) * Hn + head) * SEQn + rp * 64) * Dn;
        #pragma unroll
        for (int it2 = 0; it2 < 2; it2++) {
            int chunk = t + it2 * 256;
            int p = chunk >> 3, d0 = (chunk & 7) * 8;
            ushort tmp[8];
            #pragma unroll
            for (int e = 0; e < 8; e++) tmp[e] = f2bf(tile[p * 65 + d0 + e]);
            *(uint4*)&out[base + (size_t)p * 64 + d0] = *(const uint4*)tmp;
        }
    } else {
        size_t base = (((size_t)2 * Bn + b) * Hn + head) * (size_t)SEQn * Dn;
        #pragma unroll
        for (int it2 = 0; it2 < 2; it2++) {
            int chunk = t + it2 * 256;
            int d = chunk >> 3, pp = (chunk & 7) * 8;
            ushort tmp[8];
            #pragma unroll
            for (int e = 0; e < 8; e++) tmp[e] = f2bf(tile[(pp + e) * 65 + d]);
            *(uint4*)&out[base + (size_t)d * SEQn + rp * 64 + pp] = *(const uint4*)tmp;
        }
    }
}

// ---------------------------------------------------------------------------
// Bias in MFMA-fragment order, fp32, scaled by log2e.
__global__ __launch_bounds__(256) void bias_gather(const int* __restrict__ idx,
                                                   const float* __restrict__ pb,
                                                   float* __restrict__ rbF)
{
    const int g = blockIdx.x * 256 + threadIdx.x;   // 524288 total
    const int lane = g & 63;
    const int jt = (g >> 6) & 15;
    const int ib = (g >> 10) & 63;
    const int h  = (g >> 16) & 7;
    const int lm = lane & 15, qd = lane >> 4;
    float tmp[16];
    #pragma unroll
    for (int v = 0; v < 16; v++) {
        int r = v & 3, jb = v >> 2;
        int i = ib * 16 + qd * 4 + r;
        int j = jt * 64 + jb * 16 + lm;
        tmp[v] = 1.44269504f * pb[idx[i * 1024 + j] * 8 + h];
    }
    float* dst = rbF + ((size_t)g << 4);
    *(float4*)&dst[0]  = *(const float4*)&tmp[0];
    *(float4*)&dst[4]  = *(const float4*)&tmp[4];
    *(float4*)&dst[8]  = *(const float4*)&tmp[8];
    *(float4*)&dst[12] = *(const float4*)&tmp[12];
}

// ---------------------------------------------------------------------------
// Flash attention v5 = v3 structure (j-tile 64, no spill) + bias via MFMA
// C-init + 2-op bf16 cvt. Fixed exp bound, l via ones-MFMA.
__global__ __launch_bounds__(256) void attn_kernel(const ushort* __restrict__ qkvs,
                                                   const float* __restrict__ rbF,
                                                   const float* __restrict__ qn,
                                                   const float* __restrict__ Bmax,
                                                   const int* __restrict__ Kmaxi,
                                                   ushort* __restrict__ ao)
{
    const int n = blockIdx.x;
    const int h = n & 7, b = (n >> 3) & 15, qb = n >> 7;
    const int t = threadIdx.x, lane = t & 63, wave = t >> 6;
    const int lm = lane & 15, qd = lane >> 4;
    const int q0 = qb * 64;
    const int ib = qb * 4 + wave;
    const int i0 = q0 + wave * 16;
    const int bh = b * 8 + h;
    const size_t bhs = (size_t)bh * SEQn * Dn;
    const size_t tsz = (size_t)Bn * Hn * SEQn * Dn;
    const ushort* Q  = qkvs + bhs;
    const ushort* Kp = qkvs + tsz + bhs;          // [SEQ][D]
    const ushort* Vg = qkvs + 2 * tsz + bhs;      // [D][SEQ]

    __shared__ __align__(16) ushort Ks[64 * 72];
    __shared__ __align__(16) ushort Vt[64 * 72];
    __shared__ __align__(16) ushort PsOt[64 * 72];
    ushort* Psw = &PsOt[wave * (16 * 72)];

    short8 qf0 = *(const short8*)&Q[(size_t)(i0 + lm) * 64 + qd * 8];
    short8 qf1 = *(const short8*)&Q[(size_t)(i0 + lm) * 64 + 32 + qd * 8];

    float Mneg[4];
    {
        float kmx = __int_as_float(Kmaxi[bh]);
        float bmx = Bmax[h];
        #pragma unroll
        for (int r = 0; r < 4; r++)
            Mneg[r] = -(bmx + qn[((size_t)bh << 10) + i0 + qd * 4 + r] * kmx);
    }

    short8 ones;
    #pragma unroll
    for (int e = 0; e < 8; e++) ones[e] = (short)0x3F80;

    floatx4 oa[4], lacc;
    #pragma unroll
    for (int d = 0; d < 4; d++) oa[d] = (floatx4){0.f, 0.f, 0.f, 0.f};
    lacc = (floatx4){0.f, 0.f, 0.f, 0.f};

    const int srow = t >> 3;
    const int scol = (t & 7) * 8;

    uint4 ka, kb2, va, vb2;
    ka  = *(const uint4*)&Kp[(size_t)srow * 64 + scol];
    kb2 = *(const uint4*)&Kp[(size_t)(srow + 32) * 64 + scol];
    va  = *(const uint4*)&Vg[(size_t)srow * SEQn + scol];
    vb2 = *(const uint4*)&Vg[(size_t)(srow + 32) * SEQn + scol];

    for (int jt = 0; jt < 16; jt++) {
        __syncthreads();
        *(uint4*)&Ks[srow * 72 + scol] = ka;
        *(uint4*)&Ks[(srow + 32) * 72 + scol] = kb2;
        *(uint4*)&Vt[srow * 72 + scol] = va;
        *(uint4*)&Vt[(srow + 32) * 72 + scol] = vb2;
        if (jt < 15) {
            int j1 = (jt + 1) * 64;
            ka  = *(const uint4*)&Kp[(size_t)(j1 + srow) * 64 + scol];
            kb2 = *(const uint4*)&Kp[(size_t)(j1 + srow + 32) * 64 + scol];
            va  = *(const uint4*)&Vg[(size_t)srow * SEQn + j1 + scol];
            vb2 = *(const uint4*)&Vg[(size_t)(srow + 32) * SEQn + j1 + scol];
        }
        __syncthreads();

        const float* bp = rbF + (((((size_t)h * 64 + ib) * 16 + jt) * 64 + lane) << 4);

        // QK^T, bias+Mneg folded into the accumulator init
        floatx4 s[4];
        #pragma unroll
        for (int jb = 0; jb < 4; jb++) {
            float4 blv = *(const float4*)(bp + jb * 4);
            floatx4 z;
            z[0] = blv.x + Mneg[0];
            z[1] = blv.y + Mneg[1];
            z[2] = blv.z + Mneg[2];
            z[3] = blv.w + Mneg[3];
            short8 k0 = *(const short8*)&Ks[(jb * 16 + lm) * 72 + qd * 8];
            short8 k1 = *(const short8*)&Ks[(jb * 16 + lm) * 72 + 32 + qd * 8];
            z = __builtin_amdgcn_mfma_f32_16x16x32_bf16(qf0, k0, z, 0, 0, 0);
            z = __builtin_amdgcn_mfma_f32_16x16x32_bf16(qf1, k1, z, 0, 0, 0);
            s[jb] = z;
        }
        #pragma unroll
        for (int r = 0; r < 4; r++) {
            ushort* pr = &Psw[(qd * 4 + r) * 72 + lm];
            #pragma unroll
            for (int jb = 0; jb < 4; jb++) {
                float e = __builtin_amdgcn_exp2f(s[jb][r]);
                pr[jb * 16] = f2bf_rhu(e);
            }
        }
        short8 pf0 = *(const short8*)&Psw[lm * 72 + qd * 8];
        short8 pf1 = *(const short8*)&Psw[lm * 72 + 32 + qd * 8];
        lacc = __builtin_amdgcn_mfma_f32_16x16x32_bf16(pf0, ones, lacc, 0, 0, 0);
        lacc = __builtin_amdgcn_mfma_f32_16x16x32_bf16(pf1, ones, lacc, 0, 0, 0);
        #pragma unroll
        for (int d = 0; d < 4; d++) {
            short8 v0 = *(const short8*)&Vt[(d * 16 + lm) * 72 + qd * 8];
            short8 v1 = *(const short8*)&Vt[(d * 16 + lm) * 72 + 32 + qd * 8];
            oa[d] = __builtin_amdgcn_mfma_f32_16x16x32_bf16(pf0, v0, oa[d], 0, 0, 0);
            oa[d] = __builtin_amdgcn_mfma_f32_16x16x32_bf16(pf1, v1, oa[d], 0, 0, 0);
        }
    }
    #pragma unroll
    for (int r = 0; r < 4; r++) {
        float inv = 1.f / fmaxf(lacc[r], 1e-30f);
        #pragma unroll
        for (int d = 0; d < 4; d++)
            PsOt[(wave * 16 + qd * 4 + r) * 72 + d * 16 + lm] = f2bf(oa[d][r] * inv);
    }
    __syncthreads();
    ushort* aob = ao + ((size_t)b * SEQn + q0) * Cn + h * Dn;
    #pragma unroll
    for (int it = 0; it < 2; it++) {
        int chunk = t + it * 256;
        int i = chunk >> 3, d0 = (chunk & 7) * 8;
        *(uint4*)&aob[(size_t)i * Cn + d0] = *(const uint4*)&PsOt[i * 72 + d0];
    }
}

// ---------------------------------------------------------------------------
extern "C" void kernel_launch(void* const* d_in, const int* in_sizes, int n_in,
                              void* d_out, int out_size, void* d_ws, size_t ws_size,
                              hipStream_t stream) {
    (void)in_sizes; (void)n_in; (void)out_size; (void)ws_size;
    const float* x      = (const float*)d_in[0];
    const float* scale  = (const float*)d_in[1];
    const float* w_qkv  = (const float*)d_in[2];
    const float* dw_w_q = (const float*)d_in[3];
    const float* dw_b_q = (const float*)d_in[4];
    const float* dw_w_k = (const float*)d_in[5];
    const float* dw_b_k = (const float*)d_in[6];
    const float* dw_w_v = (const float*)d_in[7];
    const float* dw_b_v = (const float*)d_in[8];
    const float* w_out  = (const float*)d_in[9];
    const float* pos_b  = (const float*)d_in[10];
    const int*   pos_i  = (const int*)d_in[11];
    float* out = (float*)d_out;

    char* ws = (char*)d_ws;
    const size_t MB = (size_t)1 << 20;
    ushort* qkv_raw = (ushort*)(ws);              // [0,48MB)
    ushort* qkvs    = (ushort*)(ws + 48 * MB);    // [48,96MB)
    ushort* xn      = (ushort*)(ws + 48 * MB);    // [48,64MB) dead before dwconv
    ushort* wqkv_bf = (ushort*)(ws + 64 * MB);    // [64,65.5MB)
    float*  rbF     = (float*)(ws);               // [0,32MB) after dwconv
    ushort* ao      = (ushort*)(ws + 32 * MB);    // [32,48MB)
    ushort* wout_bf = (ushort*)(ws + 96 * MB);    // [96,96.5MB)
    float*  qn      = (float*)(ws + 98 * MB);     // [98,98.5MB)
    float*  Bmax    = (float*)(ws + 99 * MB);
    int*    Kmaxi   = (int*)(ws + 99 * MB + 4096);

    hipLaunchKernelGGL(cvt2_kernel, dim3(3072), dim3(256), 0, stream, w_qkv, wqkv_bf);
    hipLaunchKernelGGL(cvt2_kernel, dim3(1024), dim3(256), 0, stream, w_out, wout_bf);
    hipLaunchKernelGGL(maxpb_kernel, dim3(8), dim3(256), 0, stream, pos_b, Bmax, Kmaxi);
    hipLaunchKernelGGL(ln_kernel, dim3(256), dim3(256), 0, stream, x, scale, xn);
    hipLaunchKernelGGL(gemm_bt, dim3(8, 12, 16), dim3(256), 0, stream,
                       wqkv_bf, xn, (void*)qkv_raw, 1536, 1024, 512, 0);
    hipLaunchKernelGGL(dwconv_kernel, dim3(16, 24, 16), dim3(256), 0, stream,
                       qkv_raw, dw_w_q, dw_b_q, dw_w_k, dw_b_k, dw_w_v, dw_b_v,
                       qkvs, qn, Kmaxi);
    hipLaunchKernelGGL(bias_gather, dim3(2048), dim3(256), 0, stream, pos_i, pos_b, rbF);
    hipLaunchKernelGGL(attn_kernel, dim3(2048), dim3(256), 0, stream,
                       qkvs, rbF, qn, Bmax, Kmaxi, ao);
    hipLaunchKernelGGL(gemm_bt, dim3(8, 4, 16), dim3(256), 0, stream,
                       wout_bf, ao, (void*)out, 512, 1024, 512, 1);
}